// Round 5
// baseline (599.853 us; speedup 1.0000x reference)
//
#include <hip/hip_runtime.h>
#include <hip/hip_bf16.h>

#define NB 8
#define HWP 65536          // H*W (input/output plane stride, fixed NCHW)

typedef __attribute__((ext_vector_type(8))) short short8;
typedef __attribute__((ext_vector_type(4))) float f32x4;

__device__ __forceinline__ short f2bf(float f) {
  union { float f; unsigned u; } v; v.f = f;
  return (short)((v.u + 0x7FFF + ((v.u >> 16) & 1)) >> 16);
}
__device__ __forceinline__ float bf2f(unsigned short u) {
  union { unsigned u; float f; } v; v.u = ((unsigned)u) << 16; return v.f;
}

// ---------------- LN stats: one block per (n,c) plane, 512 threads --------
__global__ __launch_bounds__(512) void ln_stats_kernel(
    const float* __restrict__ x, const float* __restrict__ lw,
    const float* __restrict__ lb, float* __restrict__ a, float* __restrict__ b) {
  int plane = blockIdx.x;            // n*64 + c
  int c = plane & 63;
  const float4* p4 = (const float4*)(x + (size_t)plane * HWP);
  float s = 0.f, s2 = 0.f;
  for (int i = threadIdx.x; i < HWP / 4; i += 512) {
    float4 v = p4[i];
    s  += v.x + v.y + v.z + v.w;
    s2 += v.x * v.x + v.y * v.y + v.z * v.z + v.w * v.w;
  }
  for (int off = 32; off; off >>= 1) {
    s  += __shfl_down(s, off);
    s2 += __shfl_down(s2, off);
  }
  __shared__ float ls[8], ls2[8];
  int wid = threadIdx.x >> 6, lid = threadIdx.x & 63;
  if (lid == 0) { ls[wid] = s; ls2[wid] = s2; }
  __syncthreads();
  if (threadIdx.x == 0) {
    float S = 0.f, S2 = 0.f;
    for (int k = 0; k < 8; k++) { S += ls[k]; S2 += ls2[k]; }
    float mean = S * (1.f / (float)HWP);
    float var  = S2 * (1.f / (float)HWP) - mean * mean;
    float rstd = rsqrtf(var + 1e-6f);
    float av = rstd * lw[c];
    a[plane] = av;
    b[plane] = lb[c] - mean * av;
  }
}

// -------- fold LN into pw weights; emit bf16 in MFMA fragment layout ------
__global__ void fold_kernel(const float* __restrict__ w, const float* __restrict__ pb,
                            const float* __restrict__ a, const float* __restrict__ b,
                            unsigned short* __restrict__ wf16, float* __restrict__ cf, int O) {
  int idx = blockIdx.x * blockDim.x + threadIdx.x;   // n*O + o
  if (idx >= NB * O) return;
  int n = idx / O, o = idx - n * O;
  int MT = O >> 4;
  const float* an = a + n * 64;
  const float* bn = b + n * 64;
  const float* wo = w + o * 64;
  int mt = o >> 4, cl = o & 15;
  float cc = pb[o];
  for (int i = 0; i < 64; i++) {
    float wv = wo[i];
    float wf = wv * an[i];
    cc += wv * bn[i];
    int ks = i >> 5, quad = (i >> 3) & 3, j = i & 7;
    wf16[((((size_t)(n * MT + mt) * 2 + ks) * 16 + cl) * 4 + quad) * 8 + j] =
        (unsigned short)f2bf(wf);
  }
  cf[idx] = cc;
}

// -------- fold beta2 into pw4 weights (bf16 frag layout, no n dim) ---------
__global__ void fold4_kernel(const float* __restrict__ w4, const float* __restrict__ pb4,
                             const float* __restrict__ beta2,
                             unsigned short* __restrict__ wf16, float* __restrict__ cf) {
  int o = threadIdx.x;
  if (o >= 64) return;
  float bt = beta2[o];
  int mt = o >> 4, cl = o & 15;
  for (int i = 0; i < 64; i++) {
    int ks = i >> 5, quad = (i >> 3) & 3, j = i & 7;
    wf16[((((size_t)mt * 2 + ks) * 16 + cl) * 4 + quad) * 8 + j] =
        (unsigned short)f2bf(bt * w4[o * 64 + i]);
  }
  cf[o] = bt * pb4[o];
}

// ---------------- pw1 via MFMA: z[p][o] (NHWC) = W1'[n] @ x[n] + c1' ------
// z stored pixel-major [px][128ch] bf16 so dwgate reads are coalesced and
// the C-fragment store is 8 x 8B vector stores (4 consecutive channels).
__global__ __launch_bounds__(256, 2) void gemm_pw1_kernel(
    const float* __restrict__ x, const unsigned short* __restrict__ wf16,
    const float* __restrict__ cf, unsigned short* __restrict__ z) {
  int n = blockIdx.y;
  int lane = threadIdx.x & 63, wid = threadIdx.x >> 6;
  int col = lane & 15, quad = lane >> 4;
  const short8* wv8 = (const short8*)wf16 + (size_t)n * 1024;
  short8 a[8][2];
  #pragma unroll
  for (int mt = 0; mt < 8; mt++)
    #pragma unroll
    for (int ks = 0; ks < 2; ks++)
      a[mt][ks] = wv8[((mt * 2 + ks) * 16 + col) * 4 + quad];
  f32x4 cb[8];
  #pragma unroll
  for (int mt = 0; mt < 8; mt++)
    cb[mt] = *(const f32x4*)(cf + n * 128 + mt * 16 + quad * 4);
  const float* xn = x + (size_t)n * 64 * HWP;
  unsigned short* zn = z + (size_t)n * HWP * 128;
  int pxbase = blockIdx.x * 128 + wid * 16 + col;

  auto load_b = [&](int p, short8* bf) {
    #pragma unroll
    for (int ks = 0; ks < 2; ks++) {
      short8 v;
      #pragma unroll
      for (int j = 0; j < 8; j++)
        v[j] = f2bf(xn[(size_t)(ks * 32 + quad * 8 + j) * HWP + p]);
      bf[ks] = v;
    }
  };

  short8 bb[2][2];
  load_b(pxbase, bb[0]);
  #pragma unroll
  for (int tile = 0; tile < 2; tile++) {
    int cur = tile & 1, nxt = cur ^ 1;
    int p = pxbase + tile * 64;
    if (tile < 1) load_b(p + 64, bb[nxt]);
    f32x4 acc[8];
    #pragma unroll
    for (int mt = 0; mt < 8; mt++) {
      acc[mt] = cb[mt];
      acc[mt] = __builtin_amdgcn_mfma_f32_16x16x32_bf16(a[mt][0], bb[cur][0], acc[mt], 0, 0, 0);
      acc[mt] = __builtin_amdgcn_mfma_f32_16x16x32_bf16(a[mt][1], bb[cur][1], acc[mt], 0, 0, 0);
    }
    #pragma unroll
    for (int mt = 0; mt < 8; mt++) {
      uint2 pk;
      pk.x = (unsigned)(unsigned short)f2bf(acc[mt][0]) |
             ((unsigned)(unsigned short)f2bf(acc[mt][1]) << 16);
      pk.y = (unsigned)(unsigned short)f2bf(acc[mt][2]) |
             ((unsigned)(unsigned short)f2bf(acc[mt][3]) << 16);
      *(uint2*)(zn + (size_t)p * 128 + mt * 16 + quad * 4) = pk;
    }
  }
}

// ---- depthwise 3x3 + SimpleGate + pool: NHWC transpose-stencil -----------
// 1024 blocks = n(8) x strip(4, 64px) x rowband(32, 8 rows). lane = channel,
// wave = 16-px sub-strip. z reads & t writes are lane-contiguous (128B/instr).
// Rolling 3-row f32 window of 18 px (16 out + 2 halo) per plane.
__global__ __launch_bounds__(256) void dwgate_kernel(
    const unsigned short* __restrict__ z, const float* __restrict__ dww,
    const float* __restrict__ dwb, unsigned short* __restrict__ t,
    float* __restrict__ pooledp) {
  int blk = blockIdx.x;
  int n = blk >> 7, rem = blk & 127, s = rem >> 5, band = rem & 31;
  int c = threadIdx.x & 63, w = threadIdx.x >> 6;
  int cs = s * 64 + w * 16;
  int r0 = band * 8;
  const unsigned short* zn = z + (size_t)n * HWP * 128;
  unsigned short* tn = t + (size_t)n * HWP * 64;
  float w0[9], w1[9];
  #pragma unroll
  for (int k = 0; k < 9; k++) { w0[k] = dww[c * 9 + k]; w1[k] = dww[(c + 64) * 9 + k]; }
  float bias0 = dwb[c], bias1 = dwb[c + 64];
  bool lok = (cs != 0);          // px cs-1 valid?
  bool rok = (cs + 16 < 256);    // px cs+16 valid?

  float wz[2][3][18];            // [plane][row slot][m], m <-> px cs-1+m

  auto loadrow = [&](int hh, int slot) {
    if ((unsigned)hh < 256u) {
      const unsigned short* rp = zn + (size_t)hh * 256 * 128 + c;
      #pragma unroll
      for (int m = 0; m < 18; m++) {
        int px = cs - 1 + m;
        bool ok = (m == 0) ? lok : ((m == 17) ? rok : true);
        if (ok) {
          wz[0][slot][m] = bf2f(rp[(size_t)px * 128]);
          wz[1][slot][m] = bf2f(rp[(size_t)px * 128 + 64]);
        } else {
          wz[0][slot][m] = 0.f; wz[1][slot][m] = 0.f;
        }
      }
    } else {
      #pragma unroll
      for (int m = 0; m < 18; m++) { wz[0][slot][m] = 0.f; wz[1][slot][m] = 0.f; }
    }
  };

  loadrow(r0 - 1, 0);
  loadrow(r0,     1);
  float lsum = 0.f;
  #pragma unroll
  for (int i = 0; i < 8; i++) {
    const int sp = i % 3, sc = (i + 1) % 3, sn = (i + 2) % 3;
    loadrow(r0 + i + 1, sn);
    int hh = r0 + i;
    #pragma unroll
    for (int j = 0; j < 16; j++) {
      float o0 = bias0, o1 = bias1;
      o0 += w0[0] * wz[0][sp][j] + w0[1] * wz[0][sp][j + 1] + w0[2] * wz[0][sp][j + 2];
      o0 += w0[3] * wz[0][sc][j] + w0[4] * wz[0][sc][j + 1] + w0[5] * wz[0][sc][j + 2];
      o0 += w0[6] * wz[0][sn][j] + w0[7] * wz[0][sn][j + 1] + w0[8] * wz[0][sn][j + 2];
      o1 += w1[0] * wz[1][sp][j] + w1[1] * wz[1][sp][j + 1] + w1[2] * wz[1][sp][j + 2];
      o1 += w1[3] * wz[1][sc][j] + w1[4] * wz[1][sc][j + 1] + w1[5] * wz[1][sc][j + 2];
      o1 += w1[6] * wz[1][sn][j] + w1[7] * wz[1][sn][j + 1] + w1[8] * wz[1][sn][j + 2];
      float g = o0 * o1;
      tn[(size_t)(hh * 256 + cs + j) * 64 + c] = (unsigned short)f2bf(g);
      lsum += g;
    }
  }
  // per-lane = per-channel partial; reduce across the 4 waves only.
  __shared__ float red[4][64];
  red[w][c] = lsum;
  __syncthreads();
  if (threadIdx.x < 64)
    pooledp[((size_t)n * 128 + s * 32 + band) * 64 + threadIdx.x] =
        red[0][threadIdx.x] + red[1][threadIdx.x] + red[2][threadIdx.x] + red[3][threadIdx.x];
}

// ------- SCA sigmoid + fold(beta1*sca) into pw2 weights, one kernel -------
__global__ __launch_bounds__(256) void sca_fold_kernel(
    const float* __restrict__ pooledp, const float* __restrict__ sw,
    const float* __restrict__ sb, const float* __restrict__ w2,
    const float* __restrict__ pb2, const float* __restrict__ beta1,
    unsigned short* __restrict__ wf16, float* __restrict__ cf) {
  __shared__ float psum[4][64];
  __shared__ float scal[4][64];
  int ln = threadIdx.x >> 6, o = threadIdx.x & 63;
  int n = blockIdx.x * 4 + ln;
  float S = 0.f;
  for (int k = 0; k < 128; k++) S += pooledp[((size_t)n * 128 + k) * 64 + o];
  psum[ln][o] = S;
  __syncthreads();
  float s = sb[o];
  for (int i = 0; i < 64; i++)
    s += sw[o * 64 + i] * psum[ln][i] * (1.f / 65536.f);
  scal[ln][o] = 1.f / (1.f + expf(-s));
  __syncthreads();
  float bt = beta1[o];
  int mt = o >> 4, cl = o & 15;
  for (int i = 0; i < 64; i++) {
    float wf = bt * w2[o * 64 + i] * scal[ln][i];
    int ks = i >> 5, quad = (i >> 3) & 3, j = i & 7;
    wf16[((((size_t)(n * 4 + mt) * 2 + ks) * 16 + cl) * 4 + quad) * 8 + j] =
        (unsigned short)f2bf(wf);
  }
  cf[n * 64 + o] = bt * pb2[o];
}

// ---------------- pw2 + residual: x1[p][c] = x + W2' @ t + c2' -------------
// t read = one 16B vector load per ks; x1 store = 4 x float4. x residual
// stays an NCHW gather (input layout fixed). Fused LN2 partial stats.
__global__ __launch_bounds__(256, 2) void gemm_pw2_kernel(
    const unsigned short* __restrict__ t, const float* __restrict__ x,
    const unsigned short* __restrict__ wf16, const float* __restrict__ cf,
    float* __restrict__ x1, float* __restrict__ part_sum, float* __restrict__ part_sq) {
  __shared__ float red_s[4][64], red_q[4][64];
  int n = blockIdx.y;
  int lane = threadIdx.x & 63, wid = threadIdx.x >> 6;
  int col = lane & 15, quad = lane >> 4;
  const short8* wv8 = (const short8*)wf16 + (size_t)n * 512;
  short8 a[4][2];
  #pragma unroll
  for (int mt = 0; mt < 4; mt++)
    #pragma unroll
    for (int ks = 0; ks < 2; ks++)
      a[mt][ks] = wv8[((mt * 2 + ks) * 16 + col) * 4 + quad];
  f32x4 cb[4];
  #pragma unroll
  for (int mt = 0; mt < 4; mt++)
    cb[mt] = *(const f32x4*)(cf + n * 64 + mt * 16 + quad * 4);
  const unsigned short* tn = t + (size_t)n * HWP * 64;
  const float* xn = x + (size_t)n * 64 * HWP;
  float* x1n = x1 + (size_t)n * HWP * 64;
  int pxbase = blockIdx.x * 128 + wid * 16 + col;

  auto load_t = [&](int p, short8* bf) {
    #pragma unroll
    for (int ks = 0; ks < 2; ks++)
      bf[ks] = *(const short8*)(tn + (size_t)p * 64 + ks * 32 + quad * 8);
  };
  auto load_x = [&](int p, float (*xv)[4]) {
    #pragma unroll
    for (int mt = 0; mt < 4; mt++)
      #pragma unroll
      for (int r = 0; r < 4; r++)
        xv[mt][r] = xn[(size_t)(mt * 16 + quad * 4 + r) * HWP + p];
  };

  float sacc[4][4], qacc[4][4];
  #pragma unroll
  for (int mt = 0; mt < 4; mt++)
    #pragma unroll
    for (int r = 0; r < 4; r++) { sacc[mt][r] = 0.f; qacc[mt][r] = 0.f; }

  short8 bb[2][2];
  float xv[2][4][4];
  load_t(pxbase, bb[0]);
  load_x(pxbase, xv[0]);
  #pragma unroll
  for (int tile = 0; tile < 2; tile++) {
    int cur = tile & 1, nxt = cur ^ 1;
    int p = pxbase + tile * 64;
    if (tile < 1) { load_t(p + 64, bb[nxt]); load_x(p + 64, xv[nxt]); }
    f32x4 acc[4];
    #pragma unroll
    for (int mt = 0; mt < 4; mt++) {
      acc[mt] = cb[mt];
      acc[mt] = __builtin_amdgcn_mfma_f32_16x16x32_bf16(a[mt][0], bb[cur][0], acc[mt], 0, 0, 0);
      acc[mt] = __builtin_amdgcn_mfma_f32_16x16x32_bf16(a[mt][1], bb[cur][1], acc[mt], 0, 0, 0);
    }
    #pragma unroll
    for (int mt = 0; mt < 4; mt++) {
      float4 st;
      float* sv = (float*)&st;
      #pragma unroll
      for (int r = 0; r < 4; r++) {
        float v = xv[cur][mt][r] + acc[mt][r];
        sv[r] = v;
        sacc[mt][r] += v;
        qacc[mt][r] += v * v;
      }
      *(float4*)(x1n + (size_t)p * 64 + mt * 16 + quad * 4) = st;
    }
  }
  #pragma unroll
  for (int mt = 0; mt < 4; mt++)
    #pragma unroll
    for (int r = 0; r < 4; r++) {
      float s = sacc[mt][r], q = qacc[mt][r];
      #pragma unroll
      for (int off = 1; off < 16; off <<= 1) {
        s += __shfl_xor(s, off);
        q += __shfl_xor(q, off);
      }
      if (col == 0) {
        int o = mt * 16 + quad * 4 + r;
        red_s[wid][o] = s; red_q[wid][o] = q;
      }
    }
  __syncthreads();
  if (threadIdx.x < 64) {
    int cc = threadIdx.x;
    float s = red_s[0][cc] + red_s[1][cc] + red_s[2][cc] + red_s[3][cc];
    float q = red_q[0][cc] + red_q[1][cc] + red_q[2][cc] + red_q[3][cc];
    size_t pidx = ((size_t)n * 64 + cc) * 512 + blockIdx.x;
    part_sum[pidx] = s;
    part_sq[pidx]  = q;
  }
}

// -------- LN2 finalize (from gemm_pw2 partials) + fold into pw3 ------------
__global__ __launch_bounds__(256) void ln2fold_kernel(
    const float* __restrict__ w, const float* __restrict__ pb,
    const float* __restrict__ ps, const float* __restrict__ pq,
    const float* __restrict__ lw, const float* __restrict__ lb,
    unsigned short* __restrict__ wf16, float* __restrict__ cf) {
  __shared__ float aa[64], bbv[64];
  int n = blockIdx.x;
  int c = threadIdx.x >> 2, k4 = threadIdx.x & 3;
  const float* p1 = ps + ((size_t)n * 64 + c) * 512 + k4 * 128;
  const float* p2 = pq + ((size_t)n * 64 + c) * 512 + k4 * 128;
  float S = 0.f, S2 = 0.f;
  for (int k = 0; k < 128; k++) { S += p1[k]; S2 += p2[k]; }
  S  += __shfl_xor(S, 1);  S  += __shfl_xor(S, 2);
  S2 += __shfl_xor(S2, 1); S2 += __shfl_xor(S2, 2);
  if (k4 == 0) {
    float mean = S * (1.f / (float)HWP);
    float var  = S2 * (1.f / (float)HWP) - mean * mean;
    float rstd = rsqrtf(var + 1e-6f);
    float av = rstd * lw[c];
    aa[c] = av;
    bbv[c] = lb[c] - mean * av;
  }
  __syncthreads();
  if (threadIdx.x < 128) {
    int o = threadIdx.x;
    const float* wo = w + o * 64;
    int mt = o >> 4, cl = o & 15;
    float cc = pb[o];
    for (int i = 0; i < 64; i++) {
      float wv = wo[i];
      float wf = wv * aa[i];
      cc += wv * bbv[i];
      int ks = i >> 5, quad = (i >> 3) & 3, j = i & 7;
      wf16[((((size_t)(n * 8 + mt) * 2 + ks) * 16 + cl) * 4 + quad) * 8 + j] =
          (unsigned short)f2bf(wf);
    }
    cf[n * 128 + o] = cc;
  }
}

// -------- final: out = x1 + (W4'' @ gate(W3' @ x1 + c3) + c4'') ------------
// x1 NHWC: b1 = 4 x float4, residual = 4 x float4; out stays NCHW scalar.
__global__ __launch_bounds__(256, 2) void final_mfma_kernel(
    const float* __restrict__ x1, const unsigned short* __restrict__ w3f16,
    const float* __restrict__ c3f, const unsigned short* __restrict__ w4f16,
    const float* __restrict__ c4f, float* __restrict__ out) {
  __shared__ float s_c3[128];
  __shared__ __align__(16) float s_c4[64];
  int n = blockIdx.y;
  int lane = threadIdx.x & 63, wid = threadIdx.x >> 6;
  int col = lane & 15, quad = lane >> 4;
  if (threadIdx.x < 128) s_c3[threadIdx.x] = c3f[n * 128 + threadIdx.x];
  if (threadIdx.x < 64) s_c4[threadIdx.x] = c4f[threadIdx.x];
  const short8* w3v = (const short8*)w3f16 + (size_t)n * 1024;
  short8 a3[8][2];
  #pragma unroll
  for (int mt = 0; mt < 8; mt++)
    #pragma unroll
    for (int ks = 0; ks < 2; ks++)
      a3[mt][ks] = w3v[((mt * 2 + ks) * 16 + col) * 4 + quad];
  const short8* w4v = (const short8*)w4f16;
  short8 a4[4][2];
  #pragma unroll
  for (int mt = 0; mt < 4; mt++)
    #pragma unroll
    for (int ks = 0; ks < 2; ks++)
      a4[mt][ks] = w4v[((mt * 2 + ks) * 16 + col) * 4 + quad];
  __syncthreads();
  const float* x1n = x1 + (size_t)n * HWP * 64;
  float* outn = out + (size_t)n * 64 * HWP;
  int pxbase = blockIdx.x * 128 + wid * 16 + col;

  auto load_b1 = [&](int p, short8* bf) {
    #pragma unroll
    for (int ks = 0; ks < 2; ks++) {
      float4 f0 = *(const float4*)(x1n + (size_t)p * 64 + ks * 32 + quad * 8);
      float4 f1 = *(const float4*)(x1n + (size_t)p * 64 + ks * 32 + quad * 8 + 4);
      short8 v;
      v[0] = f2bf(f0.x); v[1] = f2bf(f0.y); v[2] = f2bf(f0.z); v[3] = f2bf(f0.w);
      v[4] = f2bf(f1.x); v[5] = f2bf(f1.y); v[6] = f2bf(f1.z); v[7] = f2bf(f1.w);
      bf[ks] = v;
    }
  };

  short8 bb1[2][2];
  load_b1(pxbase, bb1[0]);
  #pragma unroll
  for (int tile = 0; tile < 2; tile++) {
    int cur = tile & 1, nxt = cur ^ 1;
    int p = pxbase + tile * 64;
    if (tile < 1) load_b1(p + 64, bb1[nxt]);
    f32x4 acc[8];
    #pragma unroll
    for (int mt = 0; mt < 8; mt++) {
      acc[mt] = (f32x4){0.f, 0.f, 0.f, 0.f};
      acc[mt] = __builtin_amdgcn_mfma_f32_16x16x32_bf16(a3[mt][0], bb1[cur][0], acc[mt], 0, 0, 0);
      acc[mt] = __builtin_amdgcn_mfma_f32_16x16x32_bf16(a3[mt][1], bb1[cur][1], acc[mt], 0, 0, 0);
    }
    unsigned pd[4][2];
    #pragma unroll
    for (int mt = 0; mt < 4; mt++)
      #pragma unroll
      for (int u = 0; u < 2; u++) {
        int c0 = mt * 16 + quad * 4 + 2 * u;
        float ga = (acc[mt][2 * u]     + s_c3[c0])     * (acc[mt + 4][2 * u]     + s_c3[64 + c0]);
        float gb = (acc[mt][2 * u + 1] + s_c3[c0 + 1]) * (acc[mt + 4][2 * u + 1] + s_c3[64 + c0 + 1]);
        pd[mt][u] = (unsigned)(unsigned short)f2bf(ga) |
                    ((unsigned)(unsigned short)f2bf(gb) << 16);
      }
    short8 b2f[2];
    #pragma unroll
    for (int ks = 0; ks < 2; ks++)
      #pragma unroll
      for (int w = 0; w < 4; w++) {
        int src = ((quad & 1) * 2 + (w >> 1)) * 16 + col;
        unsigned v0 = (unsigned)__shfl((int)pd[ks * 2][w & 1], src, 64);
        unsigned v1 = (unsigned)__shfl((int)pd[ks * 2 + 1][w & 1], src, 64);
        unsigned u = (quad & 2) ? v1 : v0;
        b2f[ks][2 * w]     = (short)(u & 0xFFFFu);
        b2f[ks][2 * w + 1] = (short)(u >> 16);
      }
    f32x4 acc2[4];
    #pragma unroll
    for (int mt = 0; mt < 4; mt++) {
      acc2[mt] = *(const f32x4*)&s_c4[mt * 16 + quad * 4];
      acc2[mt] = __builtin_amdgcn_mfma_f32_16x16x32_bf16(a4[mt][0], b2f[0], acc2[mt], 0, 0, 0);
      acc2[mt] = __builtin_amdgcn_mfma_f32_16x16x32_bf16(a4[mt][1], b2f[1], acc2[mt], 0, 0, 0);
    }
    #pragma unroll
    for (int mt = 0; mt < 4; mt++) {
      float4 xr = *(const float4*)(x1n + (size_t)p * 64 + mt * 16 + quad * 4);
      const float* xv = (const float*)&xr;
      #pragma unroll
      for (int r = 0; r < 4; r++)
        outn[(size_t)(mt * 16 + quad * 4 + r) * HWP + p] = xv[r] + acc2[mt][r];
    }
  }
}

extern "C" void kernel_launch(void* const* d_in, const int* in_sizes, int n_in,
                              void* d_out, int out_size, void* d_ws, size_t ws_size,
                              hipStream_t stream) {
  const float* x    = (const float*)d_in[0];
  const float* ln1w = (const float*)d_in[1];
  const float* ln1b = (const float*)d_in[2];
  const float* pw1w = (const float*)d_in[3];
  const float* pw1b = (const float*)d_in[4];
  const float* dww  = (const float*)d_in[5];
  const float* dwb  = (const float*)d_in[6];
  const float* scaw = (const float*)d_in[7];
  const float* scab = (const float*)d_in[8];
  const float* pw2w = (const float*)d_in[9];
  const float* pw2b = (const float*)d_in[10];
  const float* ln2w = (const float*)d_in[11];
  const float* ln2b = (const float*)d_in[12];
  const float* pw3w = (const float*)d_in[13];
  const float* pw3b = (const float*)d_in[14];
  const float* pw4w = (const float*)d_in[15];
  const float* pw4b = (const float*)d_in[16];
  const float* beta1= (const float*)d_in[17];
  const float* beta2= (const float*)d_in[18];
  float* out = (float*)d_out;

  char* ws = (char*)d_ws;
  // z  (NHWC bf16): 8 x 65536 x 128 x 2B = 134,217,728
  // x1 (NHWC f32):  8 x 65536 x 64 x 4B = 134,217,728 (overlays z; z dead)
  // t  (NHWC bf16): 8 x 65536 x 64 x 2B = 67,108,864
  unsigned short* z  = (unsigned short*)ws;
  float*          x1 = (float*)ws;
  unsigned short* t  = (unsigned short*)(ws + 134217728ull);
  float* sm = (float*)(ws + 134217728ull + 67108864ull);
  float* a1 = sm;                   // 512
  float* b1 = a1 + 512;             // 512
  float* c1f = b1 + 512;            // 1024
  float* c2f = c1f + 1024;          // 512
  float* c3f = c2f + 512;           // 1024
  float* c4f = c3f + 1024;          // 64
  float* pooledp = c4f + 64;        // 8*128*64 = 65536
  unsigned short* w1f16 = (unsigned short*)(pooledp + 65536);  // 65536 us
  unsigned short* w2f16 = w1f16 + 65536;                        // 32768 us
  unsigned short* w3f16 = w2f16 + 32768;                        // 65536 us
  unsigned short* w4f16 = w3f16 + 65536;                        // 4096 us
  // LN2 partials (2 x 1MB) in d_out: consumed by ln2fold before final writes out.
  float* part_sum = (float*)d_out;
  float* part_sq  = part_sum + 262144;

  hipLaunchKernelGGL(ln_stats_kernel, dim3(512), dim3(512), 0, stream, x, ln1w, ln1b, a1, b1);
  hipLaunchKernelGGL(fold_kernel, dim3(4), dim3(256), 0, stream, pw1w, pw1b, a1, b1, w1f16, c1f, 128);
  hipLaunchKernelGGL(fold4_kernel, dim3(1), dim3(64), 0, stream, pw4w, pw4b, beta2, w4f16, c4f);
  hipLaunchKernelGGL(gemm_pw1_kernel, dim3(512, 8), dim3(256), 0, stream, x, w1f16, c1f, z);
  hipLaunchKernelGGL(dwgate_kernel, dim3(1024), dim3(256), 0, stream, z, dww, dwb, t, pooledp);
  hipLaunchKernelGGL(sca_fold_kernel, dim3(2), dim3(256), 0, stream,
                     pooledp, scaw, scab, pw2w, pw2b, beta1, w2f16, c2f);
  hipLaunchKernelGGL(gemm_pw2_kernel, dim3(512, 8), dim3(256), 0, stream, t, x, w2f16, c2f, x1,
                     part_sum, part_sq);
  hipLaunchKernelGGL(ln2fold_kernel, dim3(8), dim3(256), 0, stream,
                     pw3w, pw3b, part_sum, part_sq, ln2w, ln2b, w3f16, c3f);
  hipLaunchKernelGGL(final_mfma_kernel, dim3(512, 8), dim3(256), 0, stream,
                     x1, w3f16, c3f, w4f16, c4f, out);
}